// Round 4
// baseline (759.733 us; speedup 1.0000x reference)
//
#include <hip/hip_runtime.h>

typedef unsigned short u16;
typedef short short8 __attribute__((ext_vector_type(8)));
typedef float f32x4 __attribute__((ext_vector_type(4)));
typedef unsigned short u16x4 __attribute__((ext_vector_type(4)));

__device__ __forceinline__ u16 f2bf(float f) {
  unsigned u = __builtin_bit_cast(unsigned, f);
  u += 0x7fffu + ((u >> 16) & 1u);
  return (u16)(u >> 16);
}
__device__ __forceinline__ float bf2f(u16 s) {
  unsigned u = ((unsigned)s) << 16;
  return __builtin_bit_cast(float, u);
}

#if __has_builtin(__builtin_amdgcn_exp2f)
#define EXP2F(x) __builtin_amdgcn_exp2f(x)
#else
#define EXP2F(x) exp2f(x)
#endif

#define MFMA32(a, b, c) __builtin_amdgcn_mfma_f32_16x16x32_bf16(a, b, c, 0, 0, 0)

#define GLDS16(gp, lp)                                                         \
  __builtin_amdgcn_global_load_lds(                                            \
      (__attribute__((address_space(1))) void*)(gp),                           \
      (__attribute__((address_space(3))) void*)(lp), 16, 0, 0)

// ---------------- cast fp32 -> bf16 ----------------
__global__ __launch_bounds__(256) void cast_bf16_k(const float* __restrict__ in,
                                                   u16* __restrict__ out, int n4) {
  int i = blockIdx.x * 256 + threadIdx.x;
  if (i >= n4) return;
  float4 v = ((const float4*)in)[i];
  u16x4 o = { f2bf(v.x), f2bf(v.y), f2bf(v.z), f2bf(v.w) };
  ((u16x4*)out)[i] = o;
}

// ---------------- weight transpose+cast: Wt[n][k] = W[k][n] ----------------
__global__ __launch_bounds__(256) void transw_k(const float* W0, const float* W1,
                                                const float* W2, const float* W3,
                                                const float* W4, const float* W5,
                                                u16* __restrict__ Wt) {
  int z = blockIdx.z;
  const float* W = z == 0 ? W0 : z == 1 ? W1 : z == 2 ? W2 : z == 3 ? W3 : z == 4 ? W4 : W5;
  u16* T = Wt + (size_t)z * 2048 * 2048;
  __shared__ float tile[64][65];
  int k0 = blockIdx.x * 64, n0 = blockIdx.y * 64;
  int c4 = (threadIdx.x & 15) * 4;
  int r = threadIdx.x >> 4;  // 0..15
#pragma unroll
  for (int i = 0; i < 4; ++i) {
    int row = r + i * 16;
    float4 v = *(const float4*)(W + (size_t)(k0 + row) * 2048 + n0 + c4);
    tile[row][c4 + 0] = v.x; tile[row][c4 + 1] = v.y;
    tile[row][c4 + 2] = v.z; tile[row][c4 + 3] = v.w;
  }
  __syncthreads();
#pragma unroll
  for (int i = 0; i < 4; ++i) {
    int nrow = r + i * 16;
    u16x4 o = { f2bf(tile[c4 + 0][nrow]), f2bf(tile[c4 + 1][nrow]),
                f2bf(tile[c4 + 2][nrow]), f2bf(tile[c4 + 3][nrow]) };
    *(u16x4*)(T + (size_t)(n0 + nrow) * 2048 + k0 + c4) = o;
  }
}

// ---------------- GEMM: out = A(MxK) * Wt(NxK)^T + bias ----------------
// mode 0: bf16 out[m*ldo+n]; mode 1: bf16 out[n*ldo+perm(m)] (V^T with key
// columns permuted 16s+4q+r -> 8q+4s+r inside each 32-block, so the attention
// PV MFMA32 B-frag key indices are contiguous); mode 2: fp32 out[m*ldo+n].
struct GemmJob {
  const u16* A; const u16* Bt; const float* bias; void* out;
  int M; int mode; int ldo;
};
struct GemmJobs { GemmJob j[8]; };

__global__ __launch_bounds__(256) void gemm_k(GemmJobs jobs) {
  GemmJob J = jobs.j[blockIdx.z];
  const int m0 = blockIdx.x * 128;
  if (m0 >= J.M) return;
  const int n0 = blockIdx.y * 128;
  __shared__ u16 Asm[128 * 32];
  __shared__ u16 Bsm[128 * 32];
  const int tid = threadIdx.x;
  const int lane = tid & 63;
  const int l15 = lane & 15, quad = lane >> 4;
  const int wave = tid >> 6;
  const int wr = (wave >> 1) * 64, wc = (wave & 1) * 64;
  f32x4 acc[4][4] = {};
  const int g0 = tid, g1 = tid + 256;
  const u16* ag0 = J.A + (size_t)(m0 + (g0 >> 2)) * 2048 + (g0 & 3) * 8;
  const u16* ag1 = J.A + (size_t)(m0 + (g1 >> 2)) * 2048 + (g1 & 3) * 8;
  const u16* bg0 = J.Bt + (size_t)(n0 + (g0 >> 2)) * 2048 + (g0 & 3) * 8;
  const u16* bg1 = J.Bt + (size_t)(n0 + (g1 >> 2)) * 2048 + (g1 & 3) * 8;
  u16* al0 = Asm + g0 * 8; u16* al1 = Asm + g1 * 8;
  u16* bl0 = Bsm + g0 * 8; u16* bl1 = Bsm + g1 * 8;
  for (int k0 = 0; k0 < 2048; k0 += 32) {
    GLDS16(ag0 + k0, al0);
    GLDS16(ag1 + k0, al1);
    GLDS16(bg0 + k0, bl0);
    GLDS16(bg1 + k0, bl1);
    __syncthreads();
    short8 af[4], bf[4];
#pragma unroll
    for (int mi = 0; mi < 4; ++mi)
      af[mi] = *(const short8*)(Asm + (wr + mi * 16 + l15) * 32 + quad * 8);
#pragma unroll
    for (int ni = 0; ni < 4; ++ni)
      bf[ni] = *(const short8*)(Bsm + (wc + ni * 16 + l15) * 32 + quad * 8);
#pragma unroll
    for (int mi = 0; mi < 4; ++mi)
#pragma unroll
      for (int ni = 0; ni < 4; ++ni)
        acc[mi][ni] = __builtin_amdgcn_mfma_f32_16x16x32_bf16(af[mi], bf[ni], acc[mi][ni], 0, 0, 0);
    __syncthreads();
  }
#pragma unroll
  for (int mi = 0; mi < 4; ++mi) {
#pragma unroll
    for (int ni = 0; ni < 4; ++ni) {
      int nn = n0 + wc + ni * 16 + l15;
      float bv = J.bias[nn];
#pragma unroll
      for (int r = 0; r < 4; ++r) {
        int mm = m0 + wr + mi * 16 + quad * 4 + r;
        if (mm >= J.M) continue;
        float v = acc[mi][ni][r] + bv;
        if (J.mode == 0) {
          ((u16*)J.out)[(size_t)mm * J.ldo + nn] = f2bf(v);
        } else if (J.mode == 1) {
          int ml = mm & 31;
          int mp = (mm & ~31) | (((ml >> 2) & 3) * 8 + (ml >> 4) * 4 + (ml & 3));
          ((u16*)J.out)[(size_t)nn * J.ldo + mp] = f2bf(v);
        } else {
          ((float*)J.out)[(size_t)mm * J.ldo + nn] = v;
        }
      }
    }
  }
}

// ---------------- RMSNorm in place (rows of 2048 bf16) ----------------
__global__ __launch_bounds__(256) void rmsnorm_k(u16* __restrict__ buf,
                                                 const float* __restrict__ g) {
  const int row = blockIdx.x, tid = threadIdx.x;
  u16* p = buf + (size_t)row * 2048 + tid * 8;
  short8 v = *(short8*)p;
  float x[8]; float s = 0.f;
#pragma unroll
  for (int i = 0; i < 8; ++i) { x[i] = bf2f((u16)v[i]); s += x[i] * x[i]; }
#pragma unroll
  for (int o = 1; o < 64; o <<= 1) s += __shfl_xor(s, o, 64);
  __shared__ float ws4[4];
  if ((tid & 63) == 0) ws4[tid >> 6] = s;
  __syncthreads();
  float tot = ws4[0] + ws4[1] + ws4[2] + ws4[3];
  float scale = rsqrtf(tot * (1.0f / 2048.0f) + 1e-6f);
  const float* gp = g + tid * 8;
  short8 o8;
#pragma unroll
  for (int i = 0; i < 8; ++i) o8[i] = (short)f2bf(x[i] * scale * gp[i]);
  *(short8*)p = o8;
}

// ---------------- flash attention: LDS-staged K (XOR-swizzled) / V^T, ----------------
// 32 q-rows/wave, PV entirely in MFMA32 via the pre-permuted V^T key order.
__global__ __launch_bounds__(256, 3) void attn_k(const u16* __restrict__ Q,
                                                 const u16* __restrict__ Kt,
                                                 const u16* __restrict__ Vt,
                                                 const u16* __restrict__ Ki,
                                                 const u16* __restrict__ Vi,
                                                 const int* __restrict__ lens,
                                                 u16* __restrict__ out) {
  const int b = blockIdx.z, h = blockIdx.y;
  const int tid = threadIdx.x, lane = tid & 63, wave = tid >> 6;
  const int l15 = lane & 15, quad = lane >> 4;
  const int qbase = blockIdx.x * 128 + wave * 32;
  const float scale2 = 0.12752358514837517f;  // (1/sqrt(128)) * log2(e)
  const float NEGINF = -__builtin_inff();
  __shared__ u16 Ksm[32 * 128];  // K rows x d, 16B chunks XOR-swizzled: cc' = cc ^ (row&7)
  __shared__ u16 Vsm[128 * 32];  // d rows x 32 permuted key cols (straight)

  // Q fragments for two 16-row q-blocks (B-operand layout)
  short8 qf[2][4];
#pragma unroll
  for (int h2 = 0; h2 < 2; ++h2) {
    const u16* qb = Q + ((size_t)(b * 4096 + qbase + h2 * 16 + l15)) * 2048 + h * 128 + quad * 8;
#pragma unroll
    for (int kc = 0; kc < 4; ++kc) qf[h2][kc] = *(const short8*)(qb + kc * 32);
  }

  // staging maps (thread tid fills LDS chunk tid and chunk 256+tid)
  const int krow = tid >> 4;                          // 0..15 (second issue: +16)
  const int kcc = ((tid & 15) ^ (krow & 7)) * 8;      // swizzled source column
  const int vd = tid >> 2, vc = (tid & 3) * 8;        // V: row d, col chunk
  u16* kl0 = Ksm + tid * 8; u16* kl1 = Ksm + 2048 + tid * 8;
  u16* vl0 = Vsm + tid * 8; u16* vl1 = Vsm + 2048 + tid * 8;
  const int kxor = l15 & 7;

  f32x4 accv[2][8];
  u16x4 oimg[2][8];
  float run_m[2], run_l[2];

  auto phase = [&](const u16* Kb, const u16* Vb, int Lv, int ldv) {
    run_m[0] = run_m[1] = NEGINF;
    run_l[0] = run_l[1] = 0.f;
#pragma unroll
    for (int h2 = 0; h2 < 2; ++h2)
#pragma unroll
      for (int dt = 0; dt < 8; ++dt)
#pragma unroll
        for (int r = 0; r < 4; ++r) accv[h2][dt][r] = 0.f;
    const u16* kg0 = Kb + (size_t)krow * 2048 + kcc;
    const u16* kg1 = kg0 + 16 * 2048;
    const u16* vg0 = Vb + (size_t)vd * ldv + vc;
    const u16* vg1 = vg0 + (size_t)64 * ldv;
    const int ntiles = (Lv + 31) >> 5;
    for (int t = 0; t < ntiles; ++t) {
      const int kv0 = t * 32;
      GLDS16(kg0 + (size_t)kv0 * 2048, kl0);
      GLDS16(kg1 + (size_t)kv0 * 2048, kl1);
      GLDS16(vg0 + kv0, vl0);
      GLDS16(vg1 + kv0, vl1);
      __syncthreads();

      short8 kf0[4], kf1[4];
#pragma unroll
      for (int kc = 0; kc < 4; ++kc) {
        int c0 = ((kc * 4 + quad) ^ kxor) * 8;
        kf0[kc] = *(const short8*)(Ksm + l15 * 128 + c0);
        kf1[kc] = *(const short8*)(Ksm + (16 + l15) * 128 + c0);
      }
      f32x4 s0[2], s1[2];
#pragma unroll
      for (int h2 = 0; h2 < 2; ++h2) {
#pragma unroll
        for (int r = 0; r < 4; ++r) { s0[h2][r] = 0.f; s1[h2][r] = 0.f; }
#pragma unroll
        for (int kc = 0; kc < 4; ++kc) {
          s0[h2] = MFMA32(kf0[kc], qf[h2][kc], s0[h2]);
          s1[h2] = MFMA32(kf1[kc], qf[h2][kc], s1[h2]);
        }
      }
      // scale + tail mask
      if (kv0 + 32 <= Lv) {
#pragma unroll
        for (int h2 = 0; h2 < 2; ++h2)
#pragma unroll
          for (int r = 0; r < 4; ++r) { s0[h2][r] *= scale2; s1[h2][r] *= scale2; }
      } else {
#pragma unroll
        for (int h2 = 0; h2 < 2; ++h2)
#pragma unroll
          for (int r = 0; r < 4; ++r) {
            int k0i = kv0 + quad * 4 + r;
            s0[h2][r] = (k0i < Lv) ? s0[h2][r] * scale2 : NEGINF;
            s1[h2][r] = (k0i + 16 < Lv) ? s1[h2][r] * scale2 : NEGINF;
          }
      }
      float al[2];
      short8 pf[2];
#pragma unroll
      for (int h2 = 0; h2 < 2; ++h2) {
        float mx = fmaxf(fmaxf(fmaxf(s0[h2][0], s0[h2][1]), fmaxf(s0[h2][2], s0[h2][3])),
                         fmaxf(fmaxf(s1[h2][0], s1[h2][1]), fmaxf(s1[h2][2], s1[h2][3])));
        mx = fmaxf(mx, __shfl_xor(mx, 16, 64));
        mx = fmaxf(mx, __shfl_xor(mx, 32, 64));
        float nm = fmaxf(run_m[h2], mx);
        al[h2] = EXP2F(run_m[h2] - nm);
        run_m[h2] = nm;
        float p0[4], p1[4], psum = 0.f;
#pragma unroll
        for (int r = 0; r < 4; ++r) {
          p0[r] = EXP2F(s0[h2][r] - nm);
          p1[r] = EXP2F(s1[h2][r] - nm);
          psum += p0[r] + p1[r];
        }
        run_l[h2] = run_l[h2] * al[h2] + psum;
        pf[h2] = { (short)f2bf(p0[0]), (short)f2bf(p0[1]), (short)f2bf(p0[2]), (short)f2bf(p0[3]),
                   (short)f2bf(p1[0]), (short)f2bf(p1[1]), (short)f2bf(p1[2]), (short)f2bf(p1[3]) };
      }
      // skip accumulator rescale when no lane's max moved (al==1 exactly)
      if (__ballot((al[0] < 1.0f) || (al[1] < 1.0f))) {
#pragma unroll
        for (int h2 = 0; h2 < 2; ++h2)
#pragma unroll
          for (int dt = 0; dt < 8; ++dt)
#pragma unroll
            for (int r = 0; r < 4; ++r) accv[h2][dt][r] *= al[h2];
      }
#pragma unroll
      for (int dt = 0; dt < 8; ++dt) {
        short8 vf = *(const short8*)(Vsm + (dt * 16 + l15) * 32 + quad * 8);
        accv[0][dt] = MFMA32(vf, pf[0], accv[0][dt]);
        accv[1][dt] = MFMA32(vf, pf[1], accv[1][dt]);
      }
      __syncthreads();
    }
  };

  // ---- img phase ----
  const u16* Kb_i = Ki + (size_t)(b * 288) * 2048 + h * 128;
  const u16* Vb_i = Vi + ((size_t)(b * 16 + h) * 128) * 288;
  phase(Kb_i, Vb_i, 257, 288);
#pragma unroll
  for (int h2 = 0; h2 < 2; ++h2) {
    float a = run_l[h2] + __shfl_xor(run_l[h2], 16, 64);
    float lt = a + __shfl_xor(a, 32, 64);
    float inv = 1.0f / lt;
#pragma unroll
    for (int dt = 0; dt < 8; ++dt) {
      u16x4 w = { f2bf(accv[h2][dt][0] * inv), f2bf(accv[h2][dt][1] * inv),
                  f2bf(accv[h2][dt][2] * inv), f2bf(accv[h2][dt][3] * inv) };
      oimg[h2][dt] = w;
    }
  }
  // ---- txt phase ----
  const u16* Kb_t = Kt + (size_t)(b * 512) * 2048 + h * 128;
  const u16* Vb_t = Vt + ((size_t)(b * 16 + h) * 128) * 512;
  phase(Kb_t, Vb_t, lens[b], 512);
#pragma unroll
  for (int h2 = 0; h2 < 2; ++h2) {
    float a = run_l[h2] + __shfl_xor(run_l[h2], 16, 64);
    float lt = a + __shfl_xor(a, 32, 64);
    float inv = 1.0f / lt;
    u16* ob = out + ((size_t)(b * 4096 + qbase + h2 * 16 + l15)) * 2048 + h * 128 + quad * 4;
#pragma unroll
    for (int dt = 0; dt < 8; ++dt) {
      u16x4 w = { f2bf(bf2f(oimg[h2][dt][0]) + accv[h2][dt][0] * inv),
                  f2bf(bf2f(oimg[h2][dt][1]) + accv[h2][dt][1] * inv),
                  f2bf(bf2f(oimg[h2][dt][2]) + accv[h2][dt][2] * inv),
                  f2bf(bf2f(oimg[h2][dt][3]) + accv[h2][dt][3] * inv) };
      *(u16x4*)(ob + dt * 16) = w;
    }
  }
}

extern "C" void kernel_launch(void* const* d_in, const int* in_sizes, int n_in,
                              void* d_out, int out_size, void* d_ws, size_t ws_size,
                              hipStream_t stream) {
  const float* x   = (const float*)d_in[0];
  const float* ctx = (const float*)d_in[1];
  const int* lens  = (const int*)d_in[2];
  const float* Wq  = (const float*)d_in[3];
  const float* bq  = (const float*)d_in[4];
  const float* gq  = (const float*)d_in[5];
  const float* Wk  = (const float*)d_in[6];
  const float* bk  = (const float*)d_in[7];
  const float* gk  = (const float*)d_in[8];
  const float* Wv  = (const float*)d_in[9];
  const float* bv  = (const float*)d_in[10];
  const float* Wki = (const float*)d_in[11];
  const float* bki = (const float*)d_in[12];
  const float* gki = (const float*)d_in[13];
  const float* Wvi = (const float*)d_in[14];
  const float* bvi = (const float*)d_in[15];
  const float* Wo  = (const float*)d_in[16];
  const float* bo  = (const float*)d_in[17];
  float* out = (float*)d_out;

  char* p = (char*)d_ws;
  u16* x_bf   = (u16*)p; p += (size_t)8192 * 2048 * 2;     // reused as attn_out
  u16* ctx_bf = (u16*)p; p += (size_t)2 * 769 * 2048 * 2;
  u16* Wt     = (u16*)p; p += (size_t)6 * 2048 * 2048 * 2;
  u16* Qb     = (u16*)p; p += (size_t)8192 * 2048 * 2;
  u16* Ktxt   = (u16*)p; p += (size_t)2 * 512 * 2048 * 2;
  u16* Vtt    = (u16*)p; p += (size_t)2 * 16 * 128 * 512 * 2;
  u16* Kimg   = (u16*)p; p += (size_t)2 * 288 * 2048 * 2;
  u16* Vti    = (u16*)p; p += (size_t)2 * 16 * 128 * 288 * 2;
  u16* attn_o = x_bf;

  cast_bf16_k<<<16384, 256, 0, stream>>>(x, x_bf, 8192 * 2048 / 4);
  cast_bf16_k<<<3076, 256, 0, stream>>>(ctx, ctx_bf, 2 * 769 * 2048 / 4);
  transw_k<<<dim3(32, 32, 6), 256, 0, stream>>>(Wq, Wk, Wv, Wki, Wvi, Wo, Wt);

  GemmJobs jq = {};
  jq.j[0] = { x_bf, Wt + 0ull * 4194304, bq, Qb, 8192, 0, 2048 };
  gemm_k<<<dim3(64, 16, 1), 256, 0, stream>>>(jq);

  GemmJobs jc = {};
  for (int b = 0; b < 2; ++b) {
    const u16* txtA = ctx_bf + (size_t)(b * 769 + 257) * 2048;
    const u16* imgA = ctx_bf + (size_t)(b * 769) * 2048;
    jc.j[0 + b] = { txtA, Wt + 1ull * 4194304, bk,  Ktxt + (size_t)b * 512 * 2048, 512, 0, 2048 };
    jc.j[2 + b] = { txtA, Wt + 2ull * 4194304, bv,  Vtt  + (size_t)b * 2048 * 512, 512, 1, 512 };
    jc.j[4 + b] = { imgA, Wt + 3ull * 4194304, bki, Kimg + (size_t)b * 288 * 2048, 257, 0, 2048 };
    jc.j[6 + b] = { imgA, Wt + 4ull * 4194304, bvi, Vti  + (size_t)b * 2048 * 288, 257, 1, 288 };
  }
  gemm_k<<<dim3(4, 16, 8), 256, 0, stream>>>(jc);

  rmsnorm_k<<<8192, 256, 0, stream>>>(Qb, gq);
  rmsnorm_k<<<1024, 256, 0, stream>>>(Ktxt, gk);
  rmsnorm_k<<<576, 256, 0, stream>>>(Kimg, gki);

  attn_k<<<dim3(32, 16, 2), 256, 0, stream>>>(Qb, Ktxt, Vtt, Kimg, Vti, lens, attn_o);

  GemmJobs jo = {};
  jo.j[0] = { attn_o, Wt + 5ull * 4194304, bo, out, 8192, 2, 2048 };
  gemm_k<<<dim3(64, 16, 1), 256, 0, stream>>>(jo);
}

// Round 5
// 683.008 us; speedup vs baseline: 1.1123x; 1.1123x over previous
//
#include <hip/hip_runtime.h>

typedef unsigned short u16;
typedef short short8 __attribute__((ext_vector_type(8)));
typedef float f32x4 __attribute__((ext_vector_type(4)));
typedef unsigned short u16x4 __attribute__((ext_vector_type(4)));

__device__ __forceinline__ u16 f2bf(float f) {
  unsigned u = __builtin_bit_cast(unsigned, f);
  u += 0x7fffu + ((u >> 16) & 1u);
  return (u16)(u >> 16);
}
__device__ __forceinline__ float bf2f(u16 s) {
  unsigned u = ((unsigned)s) << 16;
  return __builtin_bit_cast(float, u);
}

#if __has_builtin(__builtin_amdgcn_exp2f)
#define EXP2F(x) __builtin_amdgcn_exp2f(x)
#else
#define EXP2F(x) exp2f(x)
#endif

#define MFMA32(a, b, c) __builtin_amdgcn_mfma_f32_16x16x32_bf16(a, b, c, 0, 0, 0)

#define GLDS16(gp, lp)                                                         \
  __builtin_amdgcn_global_load_lds(                                            \
      (__attribute__((address_space(1))) void*)(gp),                           \
      (__attribute__((address_space(3))) void*)(lp), 16, 0, 0)

// ---------------- cast fp32 -> bf16 ----------------
__global__ __launch_bounds__(256) void cast_bf16_k(const float* __restrict__ in,
                                                   u16* __restrict__ out, int n4) {
  int i = blockIdx.x * 256 + threadIdx.x;
  if (i >= n4) return;
  float4 v = ((const float4*)in)[i];
  u16x4 o = { f2bf(v.x), f2bf(v.y), f2bf(v.z), f2bf(v.w) };
  ((u16x4*)out)[i] = o;
}

// ---------------- weight transpose+cast: Wt[n][k] = W[k][n] ----------------
__global__ __launch_bounds__(256) void transw_k(const float* W0, const float* W1,
                                                const float* W2, const float* W3,
                                                const float* W4, const float* W5,
                                                u16* __restrict__ Wt) {
  int z = blockIdx.z;
  const float* W = z == 0 ? W0 : z == 1 ? W1 : z == 2 ? W2 : z == 3 ? W3 : z == 4 ? W4 : W5;
  u16* T = Wt + (size_t)z * 2048 * 2048;
  __shared__ float tile[64][65];
  int k0 = blockIdx.x * 64, n0 = blockIdx.y * 64;
  int c4 = (threadIdx.x & 15) * 4;
  int r = threadIdx.x >> 4;  // 0..15
#pragma unroll
  for (int i = 0; i < 4; ++i) {
    int row = r + i * 16;
    float4 v = *(const float4*)(W + (size_t)(k0 + row) * 2048 + n0 + c4);
    tile[row][c4 + 0] = v.x; tile[row][c4 + 1] = v.y;
    tile[row][c4 + 2] = v.z; tile[row][c4 + 3] = v.w;
  }
  __syncthreads();
#pragma unroll
  for (int i = 0; i < 4; ++i) {
    int nrow = r + i * 16;
    u16x4 o = { f2bf(tile[c4 + 0][nrow]), f2bf(tile[c4 + 1][nrow]),
                f2bf(tile[c4 + 2][nrow]), f2bf(tile[c4 + 3][nrow]) };
    *(u16x4*)(T + (size_t)(n0 + nrow) * 2048 + k0 + c4) = o;
  }
}

// ---------------- GEMM: out = A(MxK) * Wt(NxK)^T + bias ----------------
// mode 0: bf16 out[m*ldo+n]; mode 1: bf16 out[n*ldo+perm(m)] (V^T with key
// columns permuted 16s+4q+r -> 8q+4s+r inside each 32-block, so the attention
// PV MFMA32 B-frag key indices are contiguous); mode 2: fp32 out[m*ldo+n].
struct GemmJob {
  const u16* A; const u16* Bt; const float* bias; void* out;
  int M; int mode; int ldo;
};
struct GemmJobs { GemmJob j[8]; };

__global__ __launch_bounds__(256) void gemm_k(GemmJobs jobs) {
  GemmJob J = jobs.j[blockIdx.z];
  const int m0 = blockIdx.x * 128;
  if (m0 >= J.M) return;
  const int n0 = blockIdx.y * 128;
  __shared__ u16 Asm[128 * 32];
  __shared__ u16 Bsm[128 * 32];
  const int tid = threadIdx.x;
  const int lane = tid & 63;
  const int l15 = lane & 15, quad = lane >> 4;
  const int wave = tid >> 6;
  const int wr = (wave >> 1) * 64, wc = (wave & 1) * 64;
  f32x4 acc[4][4] = {};
  const int g0 = tid, g1 = tid + 256;
  const u16* ag0 = J.A + (size_t)(m0 + (g0 >> 2)) * 2048 + (g0 & 3) * 8;
  const u16* ag1 = J.A + (size_t)(m0 + (g1 >> 2)) * 2048 + (g1 & 3) * 8;
  const u16* bg0 = J.Bt + (size_t)(n0 + (g0 >> 2)) * 2048 + (g0 & 3) * 8;
  const u16* bg1 = J.Bt + (size_t)(n0 + (g1 >> 2)) * 2048 + (g1 & 3) * 8;
  u16* al0 = Asm + g0 * 8; u16* al1 = Asm + g1 * 8;
  u16* bl0 = Bsm + g0 * 8; u16* bl1 = Bsm + g1 * 8;
  for (int k0 = 0; k0 < 2048; k0 += 32) {
    GLDS16(ag0 + k0, al0);
    GLDS16(ag1 + k0, al1);
    GLDS16(bg0 + k0, bl0);
    GLDS16(bg1 + k0, bl1);
    __syncthreads();
    short8 af[4], bf[4];
#pragma unroll
    for (int mi = 0; mi < 4; ++mi)
      af[mi] = *(const short8*)(Asm + (wr + mi * 16 + l15) * 32 + quad * 8);
#pragma unroll
    for (int ni = 0; ni < 4; ++ni)
      bf[ni] = *(const short8*)(Bsm + (wc + ni * 16 + l15) * 32 + quad * 8);
#pragma unroll
    for (int mi = 0; mi < 4; ++mi)
#pragma unroll
      for (int ni = 0; ni < 4; ++ni)
        acc[mi][ni] = __builtin_amdgcn_mfma_f32_16x16x32_bf16(af[mi], bf[ni], acc[mi][ni], 0, 0, 0);
    __syncthreads();
  }
#pragma unroll
  for (int mi = 0; mi < 4; ++mi) {
#pragma unroll
    for (int ni = 0; ni < 4; ++ni) {
      int nn = n0 + wc + ni * 16 + l15;
      float bv = J.bias[nn];
#pragma unroll
      for (int r = 0; r < 4; ++r) {
        int mm = m0 + wr + mi * 16 + quad * 4 + r;
        if (mm >= J.M) continue;
        float v = acc[mi][ni][r] + bv;
        if (J.mode == 0) {
          ((u16*)J.out)[(size_t)mm * J.ldo + nn] = f2bf(v);
        } else if (J.mode == 1) {
          int ml = mm & 31;
          int mp = (mm & ~31) | (((ml >> 2) & 3) * 8 + (ml >> 4) * 4 + (ml & 3));
          ((u16*)J.out)[(size_t)nn * J.ldo + mp] = f2bf(v);
        } else {
          ((float*)J.out)[(size_t)mm * J.ldo + nn] = v;
        }
      }
    }
  }
}

// ---------------- RMSNorm in place (rows of 2048 bf16) ----------------
__global__ __launch_bounds__(256) void rmsnorm_k(u16* __restrict__ buf,
                                                 const float* __restrict__ g) {
  const int row = blockIdx.x, tid = threadIdx.x;
  u16* p = buf + (size_t)row * 2048 + tid * 8;
  short8 v = *(short8*)p;
  float x[8]; float s = 0.f;
#pragma unroll
  for (int i = 0; i < 8; ++i) { x[i] = bf2f((u16)v[i]); s += x[i] * x[i]; }
#pragma unroll
  for (int o = 1; o < 64; o <<= 1) s += __shfl_xor(s, o, 64);
  __shared__ float ws4[4];
  if ((tid & 63) == 0) ws4[tid >> 6] = s;
  __syncthreads();
  float tot = ws4[0] + ws4[1] + ws4[2] + ws4[3];
  float scale = rsqrtf(tot * (1.0f / 2048.0f) + 1e-6f);
  const float* gp = g + tid * 8;
  short8 o8;
#pragma unroll
  for (int i = 0; i < 8; ++i) o8[i] = (short)f2bf(x[i] * scale * gp[i]);
  *(short8*)p = o8;
}

// ---------------- flash attention: LDS-staged K (XOR-swizzled) / V^T, ----------------
// 32 q-rows/wave, PV entirely in MFMA32 via the pre-permuted V^T key order.
// NOTE: no min-waves pin here — 160 VGPR is intrinsic (64 acc + 32 qf + frags);
// __launch_bounds__(256,3) capped it at 84 and spilled ~640 MB/dispatch (R4).
__global__ __launch_bounds__(256) void attn_k(const u16* __restrict__ Q,
                                              const u16* __restrict__ Kt,
                                              const u16* __restrict__ Vt,
                                              const u16* __restrict__ Ki,
                                              const u16* __restrict__ Vi,
                                              const int* __restrict__ lens,
                                              u16* __restrict__ out) {
  const int b = blockIdx.z, h = blockIdx.y;
  const int tid = threadIdx.x, lane = tid & 63, wave = tid >> 6;
  const int l15 = lane & 15, quad = lane >> 4;
  const int qbase = blockIdx.x * 128 + wave * 32;
  const float scale2 = 0.12752358514837517f;  // (1/sqrt(128)) * log2(e)
  const float NEGINF = -__builtin_inff();
  __shared__ u16 Ksm[32 * 128];  // K rows x d, 16B chunks XOR-swizzled: cc' = cc ^ (row&7)
  __shared__ u16 Vsm[128 * 32];  // d rows x 32 permuted key cols (straight)

  // Q fragments for two 16-row q-blocks (B-operand layout)
  short8 qf[2][4];
#pragma unroll
  for (int h2 = 0; h2 < 2; ++h2) {
    const u16* qb = Q + ((size_t)(b * 4096 + qbase + h2 * 16 + l15)) * 2048 + h * 128 + quad * 8;
#pragma unroll
    for (int kc = 0; kc < 4; ++kc) qf[h2][kc] = *(const short8*)(qb + kc * 32);
  }

  // staging maps (thread tid fills LDS chunk tid and chunk 256+tid)
  const int krow = tid >> 4;                          // 0..15 (second issue: +16)
  const int kcc = ((tid & 15) ^ (krow & 7)) * 8;      // swizzled source column
  const int vd = tid >> 2, vc = (tid & 3) * 8;        // V: row d, col chunk
  u16* kl0 = Ksm + tid * 8; u16* kl1 = Ksm + 2048 + tid * 8;
  u16* vl0 = Vsm + tid * 8; u16* vl1 = Vsm + 2048 + tid * 8;
  const int kxor = l15 & 7;

  f32x4 accv[2][8];
  u16x4 oimg[2][8];
  float run_m[2], run_l[2];

  auto phase = [&](const u16* Kb, const u16* Vb, int Lv, int ldv) {
    run_m[0] = run_m[1] = NEGINF;
    run_l[0] = run_l[1] = 0.f;
#pragma unroll
    for (int h2 = 0; h2 < 2; ++h2)
#pragma unroll
      for (int dt = 0; dt < 8; ++dt)
#pragma unroll
        for (int r = 0; r < 4; ++r) accv[h2][dt][r] = 0.f;
    const u16* kg0 = Kb + (size_t)krow * 2048 + kcc;
    const u16* kg1 = kg0 + 16 * 2048;
    const u16* vg0 = Vb + (size_t)vd * ldv + vc;
    const u16* vg1 = vg0 + (size_t)64 * ldv;
    const int ntiles = (Lv + 31) >> 5;
    for (int t = 0; t < ntiles; ++t) {
      const int kv0 = t * 32;
      GLDS16(kg0 + (size_t)kv0 * 2048, kl0);
      GLDS16(kg1 + (size_t)kv0 * 2048, kl1);
      GLDS16(vg0 + kv0, vl0);
      GLDS16(vg1 + kv0, vl1);
      __syncthreads();

      short8 kf0[4], kf1[4];
#pragma unroll
      for (int kc = 0; kc < 4; ++kc) {
        int c0 = ((kc * 4 + quad) ^ kxor) * 8;
        kf0[kc] = *(const short8*)(Ksm + l15 * 128 + c0);
        kf1[kc] = *(const short8*)(Ksm + (16 + l15) * 128 + c0);
      }
      f32x4 s0[2], s1[2];
#pragma unroll
      for (int h2 = 0; h2 < 2; ++h2) {
#pragma unroll
        for (int r = 0; r < 4; ++r) { s0[h2][r] = 0.f; s1[h2][r] = 0.f; }
#pragma unroll
        for (int kc = 0; kc < 4; ++kc) {
          s0[h2] = MFMA32(kf0[kc], qf[h2][kc], s0[h2]);
          s1[h2] = MFMA32(kf1[kc], qf[h2][kc], s1[h2]);
        }
      }
      // scale + tail mask
      if (kv0 + 32 <= Lv) {
#pragma unroll
        for (int h2 = 0; h2 < 2; ++h2)
#pragma unroll
          for (int r = 0; r < 4; ++r) { s0[h2][r] *= scale2; s1[h2][r] *= scale2; }
      } else {
#pragma unroll
        for (int h2 = 0; h2 < 2; ++h2)
#pragma unroll
          for (int r = 0; r < 4; ++r) {
            int k0i = kv0 + quad * 4 + r;
            s0[h2][r] = (k0i < Lv) ? s0[h2][r] * scale2 : NEGINF;
            s1[h2][r] = (k0i + 16 < Lv) ? s1[h2][r] * scale2 : NEGINF;
          }
      }
      float al[2];
      short8 pf[2];
#pragma unroll
      for (int h2 = 0; h2 < 2; ++h2) {
        float mx = fmaxf(fmaxf(fmaxf(s0[h2][0], s0[h2][1]), fmaxf(s0[h2][2], s0[h2][3])),
                         fmaxf(fmaxf(s1[h2][0], s1[h2][1]), fmaxf(s1[h2][2], s1[h2][3])));
        mx = fmaxf(mx, __shfl_xor(mx, 16, 64));
        mx = fmaxf(mx, __shfl_xor(mx, 32, 64));
        float nm = fmaxf(run_m[h2], mx);
        al[h2] = EXP2F(run_m[h2] - nm);
        run_m[h2] = nm;
        float p0[4], p1[4], psum = 0.f;
#pragma unroll
        for (int r = 0; r < 4; ++r) {
          p0[r] = EXP2F(s0[h2][r] - nm);
          p1[r] = EXP2F(s1[h2][r] - nm);
          psum += p0[r] + p1[r];
        }
        run_l[h2] = run_l[h2] * al[h2] + psum;
        pf[h2] = { (short)f2bf(p0[0]), (short)f2bf(p0[1]), (short)f2bf(p0[2]), (short)f2bf(p0[3]),
                   (short)f2bf(p1[0]), (short)f2bf(p1[1]), (short)f2bf(p1[2]), (short)f2bf(p1[3]) };
      }
      // skip accumulator rescale when no lane's max moved (al==1 exactly)
      if (__ballot((al[0] < 1.0f) || (al[1] < 1.0f))) {
#pragma unroll
        for (int h2 = 0; h2 < 2; ++h2)
#pragma unroll
          for (int dt = 0; dt < 8; ++dt)
#pragma unroll
            for (int r = 0; r < 4; ++r) accv[h2][dt][r] *= al[h2];
      }
#pragma unroll
      for (int dt = 0; dt < 8; ++dt) {
        short8 vf = *(const short8*)(Vsm + (dt * 16 + l15) * 32 + quad * 8);
        accv[0][dt] = MFMA32(vf, pf[0], accv[0][dt]);
        accv[1][dt] = MFMA32(vf, pf[1], accv[1][dt]);
      }
      __syncthreads();
    }
  };

  // ---- img phase ----
  const u16* Kb_i = Ki + (size_t)(b * 288) * 2048 + h * 128;
  const u16* Vb_i = Vi + ((size_t)(b * 16 + h) * 128) * 288;
  phase(Kb_i, Vb_i, 257, 288);
#pragma unroll
  for (int h2 = 0; h2 < 2; ++h2) {
    float a = run_l[h2] + __shfl_xor(run_l[h2], 16, 64);
    float lt = a + __shfl_xor(a, 32, 64);
    float inv = 1.0f / lt;
#pragma unroll
    for (int dt = 0; dt < 8; ++dt) {
      u16x4 w = { f2bf(accv[h2][dt][0] * inv), f2bf(accv[h2][dt][1] * inv),
                  f2bf(accv[h2][dt][2] * inv), f2bf(accv[h2][dt][3] * inv) };
      oimg[h2][dt] = w;
    }
  }
  // ---- txt phase ----
  const u16* Kb_t = Kt + (size_t)(b * 512) * 2048 + h * 128;
  const u16* Vb_t = Vt + ((size_t)(b * 16 + h) * 128) * 512;
  phase(Kb_t, Vb_t, lens[b], 512);
#pragma unroll
  for (int h2 = 0; h2 < 2; ++h2) {
    float a = run_l[h2] + __shfl_xor(run_l[h2], 16, 64);
    float lt = a + __shfl_xor(a, 32, 64);
    float inv = 1.0f / lt;
    u16* ob = out + ((size_t)(b * 4096 + qbase + h2 * 16 + l15)) * 2048 + h * 128 + quad * 4;
#pragma unroll
    for (int dt = 0; dt < 8; ++dt) {
      u16x4 w = { f2bf(bf2f(oimg[h2][dt][0]) + accv[h2][dt][0] * inv),
                  f2bf(bf2f(oimg[h2][dt][1]) + accv[h2][dt][1] * inv),
                  f2bf(bf2f(oimg[h2][dt][2]) + accv[h2][dt][2] * inv),
                  f2bf(bf2f(oimg[h2][dt][3]) + accv[h2][dt][3] * inv) };
      *(u16x4*)(ob + dt * 16) = w;
    }
  }
}

extern "C" void kernel_launch(void* const* d_in, const int* in_sizes, int n_in,
                              void* d_out, int out_size, void* d_ws, size_t ws_size,
                              hipStream_t stream) {
  const float* x   = (const float*)d_in[0];
  const float* ctx = (const float*)d_in[1];
  const int* lens  = (const int*)d_in[2];
  const float* Wq  = (const float*)d_in[3];
  const float* bq  = (const float*)d_in[4];
  const float* gq  = (const float*)d_in[5];
  const float* Wk  = (const float*)d_in[6];
  const float* bk  = (const float*)d_in[7];
  const float* gk  = (const float*)d_in[8];
  const float* Wv  = (const float*)d_in[9];
  const float* bv  = (const float*)d_in[10];
  const float* Wki = (const float*)d_in[11];
  const float* bki = (const float*)d_in[12];
  const float* gki = (const float*)d_in[13];
  const float* Wvi = (const float*)d_in[14];
  const float* bvi = (const float*)d_in[15];
  const float* Wo  = (const float*)d_in[16];
  const float* bo  = (const float*)d_in[17];
  float* out = (float*)d_out;

  char* p = (char*)d_ws;
  u16* x_bf   = (u16*)p; p += (size_t)8192 * 2048 * 2;     // reused as attn_out
  u16* ctx_bf = (u16*)p; p += (size_t)2 * 769 * 2048 * 2;
  u16* Wt     = (u16*)p; p += (size_t)6 * 2048 * 2048 * 2;
  u16* Qb     = (u16*)p; p += (size_t)8192 * 2048 * 2;
  u16* Ktxt   = (u16*)p; p += (size_t)2 * 512 * 2048 * 2;
  u16* Vtt    = (u16*)p; p += (size_t)2 * 16 * 128 * 512 * 2;
  u16* Kimg   = (u16*)p; p += (size_t)2 * 288 * 2048 * 2;
  u16* Vti    = (u16*)p; p += (size_t)2 * 16 * 128 * 288 * 2;
  u16* attn_o = x_bf;

  cast_bf16_k<<<16384, 256, 0, stream>>>(x, x_bf, 8192 * 2048 / 4);
  cast_bf16_k<<<3076, 256, 0, stream>>>(ctx, ctx_bf, 2 * 769 * 2048 / 4);
  transw_k<<<dim3(32, 32, 6), 256, 0, stream>>>(Wq, Wk, Wv, Wki, Wvi, Wo, Wt);

  GemmJobs jq = {};
  jq.j[0] = { x_bf, Wt + 0ull * 4194304, bq, Qb, 8192, 0, 2048 };
  gemm_k<<<dim3(64, 16, 1), 256, 0, stream>>>(jq);

  GemmJobs jc = {};
  for (int b = 0; b < 2; ++b) {
    const u16* txtA = ctx_bf + (size_t)(b * 769 + 257) * 2048;
    const u16* imgA = ctx_bf + (size_t)(b * 769) * 2048;
    jc.j[0 + b] = { txtA, Wt + 1ull * 4194304, bk,  Ktxt + (size_t)b * 512 * 2048, 512, 0, 2048 };
    jc.j[2 + b] = { txtA, Wt + 2ull * 4194304, bv,  Vtt  + (size_t)b * 2048 * 512, 512, 1, 512 };
    jc.j[4 + b] = { imgA, Wt + 3ull * 4194304, bki, Kimg + (size_t)b * 288 * 2048, 257, 0, 2048 };
    jc.j[6 + b] = { imgA, Wt + 4ull * 4194304, bvi, Vti  + (size_t)b * 2048 * 288, 257, 1, 288 };
  }
  gemm_k<<<dim3(4, 16, 8), 256, 0, stream>>>(jc);

  rmsnorm_k<<<8192, 256, 0, stream>>>(Qb, gq);
  rmsnorm_k<<<1024, 256, 0, stream>>>(Ktxt, gk);
  rmsnorm_k<<<576, 256, 0, stream>>>(Kimg, gki);

  attn_k<<<dim3(32, 16, 2), 256, 0, stream>>>(Qb, Ktxt, Vtt, Kimg, Vti, lens, attn_o);

  GemmJobs jo = {};
  jo.j[0] = { attn_o, Wt + 5ull * 4194304, bo, out, 8192, 2, 2048 };
  gemm_k<<<dim3(64, 16, 1), 256, 0, stream>>>(jo);
}